// Round 2
// baseline (1021.014 us; speedup 1.0000x reference)
//
#include <hip/hip_runtime.h>

namespace {
constexpr int SEQ = 1024;
constexpr int DHEAD = 64;
constexpr int NHEADS = 16;
constexpr int QB = 32;               // query rows per block
constexpr int RB = 64;               // key rows per tile
constexpr int PEROWS = QB + RB - 1;  // 95 dist_emb rows needed per tile
constexpr int PADW = 68;             // padded row stride (floats), 16B-aligned
constexpr int SBROW = 65;            // prob-buffer row stride
}

// ---------------- fused QKV projection: dst[bh][s][d] = X @ W^T + bias --------
// grid.z in {0,1,2} selects which of {Q,K,V} this block computes.
__global__ __launch_bounds__(256) void proj_kernel(
    const float* __restrict__ X,
    const float* __restrict__ Wq, const float* __restrict__ Bq,
    const float* __restrict__ Wk, const float* __restrict__ Bk,
    const float* __restrict__ Wv, const float* __restrict__ Bv,
    float* __restrict__ ws) {
  __shared__ float As[16][PADW];  // As[k][m]
  __shared__ float Bs[16][PADW];  // Bs[k][n]
  const int which = blockIdx.z;
  const float* W = (which == 0) ? Wq : (which == 1) ? Wk : Wv;
  const float* bias = (which == 0) ? Bq : (which == 1) ? Bk : Bv;
  float* dst = ws + (size_t)which * (64u * SEQ * DHEAD);
  const int m0 = blockIdx.x * 64;
  const int n0 = blockIdx.y * 64;
  const int tid = threadIdx.x;
  const int tm = tid & 15, tn = tid >> 4;
  const int lrow = tid >> 2;        // 0..63
  const int lk4 = (tid & 3) << 2;   // 0,4,8,12
  float acc[4][4] = {};
  for (int k0 = 0; k0 < 1024; k0 += 16) {
    const float4 a4 = *(const float4*)(X + (size_t)(m0 + lrow) * 1024 + k0 + lk4);
    const float4 b4 = *(const float4*)(W + (size_t)(n0 + lrow) * 1024 + k0 + lk4);
    __syncthreads();
    As[lk4 + 0][lrow] = a4.x; As[lk4 + 1][lrow] = a4.y;
    As[lk4 + 2][lrow] = a4.z; As[lk4 + 3][lrow] = a4.w;
    Bs[lk4 + 0][lrow] = b4.x; Bs[lk4 + 1][lrow] = b4.y;
    Bs[lk4 + 2][lrow] = b4.z; Bs[lk4 + 3][lrow] = b4.w;
    __syncthreads();
#pragma unroll
    for (int kk = 0; kk < 16; ++kk) {
      const float4 av = *(const float4*)&As[kk][tm << 2];
      const float4 bv = *(const float4*)&Bs[kk][tn << 2];
      const float aa[4] = {av.x, av.y, av.z, av.w};
      const float bb[4] = {bv.x, bv.y, bv.z, bv.w};
#pragma unroll
      for (int i = 0; i < 4; ++i)
#pragma unroll
        for (int j = 0; j < 4; ++j)
          acc[i][j] = fmaf(aa[i], bb[j], acc[i][j]);
    }
  }
  // n0 is a multiple of 64 -> whole block maps to one head h = n0/64
  const int h = n0 >> 6;
  const int dbase = tn << 2;
#pragma unroll
  for (int i = 0; i < 4; ++i) {
    const int mm = m0 + (tm << 2) + i;
    const int b = mm >> 10, s = mm & 1023;
    float4 o;
    o.x = acc[i][0] + bias[n0 + dbase + 0];
    o.y = acc[i][1] + bias[n0 + dbase + 1];
    o.z = acc[i][2] + bias[n0 + dbase + 2];
    o.w = acc[i][3] + bias[n0 + dbase + 3];
    *(float4*)(dst + ((size_t)(b * NHEADS + h) * SEQ + s) * DHEAD + dbase) = o;
  }
}

// ---------------- fused relative-position attention (flash-style) ----------------
// grid: x = B*H (64), y = SEQ/QB (32); 256 threads = 8 lanes per query row.
__global__ __launch_bounds__(256) void attn_kernel(
    const float* __restrict__ Qg, const float* __restrict__ Kg,
    const float* __restrict__ Vg, const float* __restrict__ dist,
    float* __restrict__ out) {
  __shared__ float ks[RB][PADW];
  __shared__ float vs[RB][PADW];
  __shared__ float peu[PEROWS * PADW];  // pe tile; aliased as prob buffer after use
  const int bh = blockIdx.x;
  const int l0 = blockIdx.y * QB;
  const int b = bh >> 4, h = bh & 15;
  const int tid = threadIdx.x;
  const int l = tid >> 3;   // local query row 0..31 (8 threads per row)
  const int rg = tid & 7;   // lane group within row

  // q row: each lane loads its own 8 floats; full row reassembled via shfl.
  float4 qown0, qown1;
  {
    const float* qrow = Qg + ((size_t)bh * SEQ + l0 + l) * DHEAD + (rg << 3);
    qown0 = *(const float4*)(qrow);
    qown1 = *(const float4*)(qrow + 4);
  }
  // reassemble the full 64-float q row into registers via 8-lane shfl
  float qreg[64];
#pragma unroll
  for (int src = 0; src < 8; ++src) {
    // value held by lane (tid & ~7) + src
    qreg[src * 8 + 0] = __shfl(qown0.x, src, 8);
    qreg[src * 8 + 1] = __shfl(qown0.y, src, 8);
    qreg[src * 8 + 2] = __shfl(qown0.z, src, 8);
    qreg[src * 8 + 3] = __shfl(qown0.w, src, 8);
    qreg[src * 8 + 4] = __shfl(qown1.x, src, 8);
    qreg[src * 8 + 5] = __shfl(qown1.y, src, 8);
    qreg[src * 8 + 6] = __shfl(qown1.z, src, 8);
    qreg[src * 8 + 7] = __shfl(qown1.w, src, 8);
  }

  float mrun = -1e30f, denom = 0.f;
  float4 acc0 = {0.f, 0.f, 0.f, 0.f}, acc1 = {0.f, 0.f, 0.f, 0.f};

  for (int r0 = 0; r0 < SEQ; r0 += RB) {
    __syncthreads();  // previous tile fully consumed before overwrite
    // stage K, V tiles (coalesced float4)
#pragma unroll
    for (int it = 0; it < 4; ++it) {
      const int flat = (it * 256 + tid) * 4;
      const int row = flat >> 6, col = flat & 63;
      *(float4*)&ks[row][col] =
          *(const float4*)(Kg + ((size_t)bh * SEQ + r0 + row) * DHEAD + col);
      *(float4*)&vs[row][col] =
          *(const float4*)(Vg + ((size_t)bh * SEQ + r0 + row) * DHEAD + col);
    }
    // stage the 95 dist_emb rows: global p = (l0+l) - (r0+r) + 1023
    const int pbase = l0 - r0 + 960;  // in [0, 1952]
#pragma unroll
    for (int it = 0; it < 6; ++it) {
      const int flat = it * 1024 + tid * 4;
      if (flat < PEROWS * 64) {
        const int row = flat >> 6, col = flat & 63;
        *(float4*)&peu[row * PADW + col] =
            *(const float4*)(dist + (size_t)(pbase + row) * DHEAD + col);
      }
    }
    __syncthreads();

    // scores: s = q·k + (q+k)·pe   (thread handles r = rg + 8j, j=0..7)
    float sc[8];
#pragma unroll
    for (int j = 0; j < 8; ++j) sc[j] = 0.f;
#pragma unroll
    for (int d4 = 0; d4 < 16; ++d4) {
      const int d0 = d4 << 2;
      const float q0 = qreg[d0 + 0], q1 = qreg[d0 + 1];
      const float q2 = qreg[d0 + 2], q3 = qreg[d0 + 3];
#pragma unroll
      for (int j = 0; j < 8; ++j) {
        const int r = rg + (j << 3);
        const float4 k4 = *(const float4*)&ks[r][d0];
        const float4 p4 = *(const float4*)&peu[(l - r + 63) * PADW + d0];
        sc[j] = fmaf(q0, k4.x, sc[j]); sc[j] = fmaf(q0 + k4.x, p4.x, sc[j]);
        sc[j] = fmaf(q1, k4.y, sc[j]); sc[j] = fmaf(q1 + k4.y, p4.y, sc[j]);
        sc[j] = fmaf(q2, k4.z, sc[j]); sc[j] = fmaf(q2 + k4.z, p4.z, sc[j]);
        sc[j] = fmaf(q3, k4.w, sc[j]); sc[j] = fmaf(q3 + k4.w, p4.w, sc[j]);
      }
    }

    // online softmax (8-lane groups, aligned -> shfl_xor 1/2/4 stays in group)
    float tmax = -1e30f;
#pragma unroll
    for (int j = 0; j < 8; ++j) { sc[j] *= 0.125f; tmax = fmaxf(tmax, sc[j]); }
    tmax = fmaxf(tmax, __shfl_xor(tmax, 1));
    tmax = fmaxf(tmax, __shfl_xor(tmax, 2));
    tmax = fmaxf(tmax, __shfl_xor(tmax, 4));
    const float newm = fmaxf(mrun, tmax);
    const float fresc = __expf(mrun - newm);
    mrun = newm;

    __syncthreads();  // all pe reads done -> reuse peu as prob buffer
    float psum = 0.f;
#pragma unroll
    for (int j = 0; j < 8; ++j) {
      const float p = __expf(sc[j] - newm);
      peu[l * SBROW + rg + (j << 3)] = p;
      psum += p;
    }
    psum += __shfl_xor(psum, 1);
    psum += __shfl_xor(psum, 2);
    psum += __shfl_xor(psum, 4);
    denom = denom * fresc + psum;
    acc0.x *= fresc; acc0.y *= fresc; acc0.z *= fresc; acc0.w *= fresc;
    acc1.x *= fresc; acc1.y *= fresc; acc1.z *= fresc; acc1.w *= fresc;
    __syncthreads();  // probs visible

    // PV: thread owns d = rg*8 .. rg*8+7 of its row
    const int dbase = rg << 3;
#pragma unroll 4
    for (int r = 0; r < RB; ++r) {
      const float pr = peu[l * SBROW + r];
      const float4 v0 = *(const float4*)&vs[r][dbase];
      const float4 v1 = *(const float4*)&vs[r][dbase + 4];
      acc0.x = fmaf(pr, v0.x, acc0.x); acc0.y = fmaf(pr, v0.y, acc0.y);
      acc0.z = fmaf(pr, v0.z, acc0.z); acc0.w = fmaf(pr, v0.w, acc0.w);
      acc1.x = fmaf(pr, v1.x, acc1.x); acc1.y = fmaf(pr, v1.y, acc1.y);
      acc1.z = fmaf(pr, v1.z, acc1.z); acc1.w = fmaf(pr, v1.w, acc1.w);
    }
  }

  const float inv = 1.f / denom;
  const int dbase = rg << 3;
  float4 o0, o1;
  o0.x = acc0.x * inv; o0.y = acc0.y * inv; o0.z = acc0.z * inv; o0.w = acc0.w * inv;
  o1.x = acc1.x * inv; o1.y = acc1.y * inv; o1.z = acc1.z * inv; o1.w = acc1.w * inv;
  float* orow = out + ((size_t)b * SEQ + l0 + l) * 1024 + h * DHEAD + dbase;
  *(float4*)orow = o0;
  *(float4*)(orow + 4) = o1;
}

extern "C" void kernel_launch(void* const* d_in, const int* in_sizes, int n_in,
                              void* d_out, int out_size, void* d_ws, size_t ws_size,
                              hipStream_t stream) {
  const float* hs = (const float*)d_in[0];
  const float* wq = (const float*)d_in[1];
  const float* bq = (const float*)d_in[2];
  const float* wk = (const float*)d_in[3];
  const float* bk = (const float*)d_in[4];
  const float* wv = (const float*)d_in[5];
  const float* bv = (const float*)d_in[6];
  const float* de = (const float*)d_in[7];
  float* out = (float*)d_out;

  const size_t QSZ = (size_t)64 * SEQ * DHEAD;  // 4 Mi floats per tensor
  float* q = (float*)d_ws;
  float* k = q + QSZ;
  float* v = k + QSZ;

  dim3 pgrid(64, 16, 3);
  proj_kernel<<<pgrid, 256, 0, stream>>>(hs, wq, bq, wk, bk, wv, bv, (float*)d_ws);

  dim3 agrid(64, 32);
  attn_kernel<<<agrid, 256, 0, stream>>>(q, k, v, de, out);
}

// Round 3
// 427.627 us; speedup vs baseline: 2.3876x; 2.3876x over previous
//
#include <hip/hip_runtime.h>

typedef __attribute__((ext_vector_type(8))) short bf16x8;
typedef __attribute__((ext_vector_type(4))) float f32x4;
typedef __attribute__((ext_vector_type(4))) unsigned short u16x4;
typedef __attribute__((ext_vector_type(8))) unsigned short u16x8;

__device__ __forceinline__ unsigned short f2bf(float f) {
  union { float f; unsigned u; } v; v.f = f;
  unsigned r = v.u + 0x7FFFu + ((v.u >> 16) & 1u);  // RNE
  return (unsigned short)(r >> 16);
}
__device__ __forceinline__ float bf2f(unsigned short h) {
  union { unsigned u; float f; } v; v.u = ((unsigned)h) << 16;
  return v.f;
}

// ---------------- QKV projection, bf16 MFMA: dst[bh][s][d] = X @ W^T + b ------
// grid (32, 8, 3): 128x128 tile, 4 waves x 64x64, BK=64. z selects Q/K/V.
__global__ __launch_bounds__(256) void proj_mfma(
    const float* __restrict__ X,
    const float* __restrict__ Wq, const float* __restrict__ Bq,
    const float* __restrict__ Wk, const float* __restrict__ Bk,
    const float* __restrict__ Wv, const float* __restrict__ Bv,
    unsigned short* __restrict__ ws) {
  __shared__ unsigned short As[128 * 72];
  __shared__ unsigned short Bs[128 * 72];
  const int which = blockIdx.z;
  const float* W = which == 0 ? Wq : which == 1 ? Wk : Wv;
  const float* bias = which == 0 ? Bq : which == 1 ? Bk : Bv;
  unsigned short* dst = ws + (size_t)which * (4096u * 1024u);
  const int m0 = blockIdx.x * 128, n0 = blockIdx.y * 128;
  const int tid = threadIdx.x;
  const int wid = tid >> 6, lane = tid & 63;
  const int lrow = lane & 15, lgrp = lane >> 4;
  const int wr0 = (wid >> 1) * 64, wc0 = (wid & 1) * 64;
  const int srow = tid & 127, scol0 = (tid >> 7) * 32;  // staging: 32 elems/thread

  f32x4 acc[4][4] = {};
  for (int k0 = 0; k0 < 1024; k0 += 64) {
    float4 a[8], b[8];
    const float* Ap = X + (size_t)(m0 + srow) * 1024 + k0 + scol0;
    const float* Bp = W + (size_t)(n0 + srow) * 1024 + k0 + scol0;
#pragma unroll
    for (int j = 0; j < 8; ++j) {
      a[j] = *(const float4*)(Ap + j * 4);
      b[j] = *(const float4*)(Bp + j * 4);
    }
    __syncthreads();
#pragma unroll
    for (int j = 0; j < 8; ++j) {
      u16x4 pa, pb;
      pa[0] = f2bf(a[j].x); pa[1] = f2bf(a[j].y); pa[2] = f2bf(a[j].z); pa[3] = f2bf(a[j].w);
      pb[0] = f2bf(b[j].x); pb[1] = f2bf(b[j].y); pb[2] = f2bf(b[j].z); pb[3] = f2bf(b[j].w);
      *(u16x4*)&As[srow * 72 + scol0 + j * 4] = pa;
      *(u16x4*)&Bs[srow * 72 + scol0 + j * 4] = pb;
    }
    __syncthreads();
#pragma unroll
    for (int ks = 0; ks < 2; ++ks) {
      bf16x8 af[4], bfr[4];
#pragma unroll
      for (int rb = 0; rb < 4; ++rb)
        af[rb] = *(const bf16x8*)&As[(wr0 + rb * 16 + lrow) * 72 + ks * 32 + lgrp * 8];
#pragma unroll
      for (int cb = 0; cb < 4; ++cb)
        bfr[cb] = *(const bf16x8*)&Bs[(wc0 + cb * 16 + lrow) * 72 + ks * 32 + lgrp * 8];
#pragma unroll
      for (int rb = 0; rb < 4; ++rb)
#pragma unroll
        for (int cb = 0; cb < 4; ++cb)
          acc[rb][cb] = __builtin_amdgcn_mfma_f32_16x16x32_bf16(af[rb], bfr[cb], acc[rb][cb], 0, 0, 0);
    }
  }
  // epilogue: +bias, cvt bf16, write to [b][h][s][d]
#pragma unroll
  for (int cb = 0; cb < 4; ++cb) {
    const int n = n0 + wc0 + cb * 16 + lrow;
    const float bval = bias[n];
    const int h = n >> 6, d = n & 63;
#pragma unroll
    for (int rb = 0; rb < 4; ++rb)
#pragma unroll
      for (int reg = 0; reg < 4; ++reg) {
        const int m = m0 + wr0 + rb * 16 + lgrp * 4 + reg;
        const int b_ = m >> 10, s_ = m & 1023;
        dst[(((size_t)(b_ * 16 + h) * 1024 + s_) << 6) | d] = f2bf(acc[rb][cb][reg] + bval);
      }
  }
}

// ---------------- dist_emb fp32 -> bf16 (2047*64 = 131008 elems) --------------
__global__ __launch_bounds__(256) void cvt_dist(const float* __restrict__ in,
                                                unsigned short* __restrict__ out) {
  const int idx = (blockIdx.x * 256 + threadIdx.x) * 4;
  if (idx < 131008) {
    const float4 f = *(const float4*)(in + idx);
    u16x4 p;
    p[0] = f2bf(f.x); p[1] = f2bf(f.y); p[2] = f2bf(f.z); p[3] = f2bf(f.w);
    *(u16x4*)(out + idx) = p;
  }
}

// ---------------- V[bh][s][d] -> Vt[bh][d][s] transpose (bf16) ----------------
__global__ __launch_bounds__(256) void transpose_v(const unsigned short* __restrict__ V,
                                                   unsigned short* __restrict__ Vt) {
  __shared__ unsigned short t[64 * 72];
  const int bh = blockIdx.x, s0 = blockIdx.y * 64;
  const int tid = threadIdx.x;
  const int row = tid >> 2, c0 = (tid & 3) * 16;
  const unsigned short* src = V + ((size_t)bh * 1024 + s0 + row) * 64 + c0;
  const u16x8 v0 = *(const u16x8*)src;
  const u16x8 v1 = *(const u16x8*)(src + 8);
  *(u16x8*)&t[row * 72 + c0] = v0;
  *(u16x8*)&t[row * 72 + c0 + 8] = v1;
  __syncthreads();
  // write: row d = tid>>2, s-cols c0..c0+15
  u16x8 o0, o1;
#pragma unroll
  for (int j = 0; j < 8; ++j) o0[j] = t[(c0 + j) * 72 + row];
#pragma unroll
  for (int j = 0; j < 8; ++j) o1[j] = t[(c0 + 8 + j) * 72 + row];
  unsigned short* dstp = Vt + ((size_t)bh * 64 + row) * 1024 + s0 + c0;
  *(u16x8*)dstp = o0;
  *(u16x8*)(dstp + 8) = o1;
}

// ---------------- fused rel-pos attention, bf16 MFMA --------------------------
// grid (64 bh, 16 q-blocks), 256 thr = 4 waves. Q-tile 64, K-tile 64.
// scores = Q.K^T + gather(U) + gather(W); U = Q.PE^T, W = K.PE^T (per-tile GEMMs).
__global__ __launch_bounds__(256) void attn_mfma(
    const unsigned short* __restrict__ Qg, const unsigned short* __restrict__ Kg,
    const unsigned short* __restrict__ Vtg, const unsigned short* __restrict__ PEg,
    float* __restrict__ out) {
  __shared__ unsigned short Ks[64 * 72];    // K tile [r][d]
  __shared__ unsigned short Vts[64 * 72];   // V^T tile [d][r]
  __shared__ unsigned short PEs[128 * 72];  // pe rows [p][d] (127 used)
  __shared__ unsigned short Ub[64 * 132];   // U[l][p] bf16
  __shared__ unsigned short Wb[64 * 132];   // W[r][p] bf16
  __shared__ unsigned short Ps[64 * 72];    // Q staging first, then P[l][r]

  const int bh = blockIdx.x;
  const int l0 = blockIdx.y * 64;
  const int b = bh >> 4, h = bh & 15;
  const int tid = threadIdx.x;
  const int wid = tid >> 6, lane = tid & 63;
  const int lrow = lane & 15, lgrp = lane >> 4;
  const int rbase = (wid & 1) * 32;  // U/W row base for this wave

  // ---- stage Q (into Ps) and hoist A-fragments ----
  {
    const unsigned short* qsrc = Qg + ((size_t)bh * 1024 + l0 + (tid >> 2)) * 64 + (tid & 3) * 16;
    const u16x8 q0 = *(const u16x8*)qsrc;
    const u16x8 q1 = *(const u16x8*)(qsrc + 8);
    *(u16x8*)&Ps[(tid >> 2) * 72 + (tid & 3) * 16] = q0;
    *(u16x8*)&Ps[(tid >> 2) * 72 + (tid & 3) * 16 + 8] = q1;
  }
  __syncthreads();
  bf16x8 qaS[2];  // Q rows 16*wid.., for Sqk
#pragma unroll
  for (int ks = 0; ks < 2; ++ks)
    qaS[ks] = *(const bf16x8*)&Ps[(wid * 16 + lrow) * 72 + ks * 32 + lgrp * 8];
  bf16x8 qaU[2][2];  // waves 0,1: Q rows rbase+rb*16.., for U GEMM
  if (wid < 2) {
#pragma unroll
    for (int rb = 0; rb < 2; ++rb)
#pragma unroll
      for (int ks = 0; ks < 2; ++ks)
        qaU[rb][ks] = *(const bf16x8*)&Ps[(rbase + rb * 16 + lrow) * 72 + ks * 32 + lgrp * 8];
  }

  float m[4], den[4];
#pragma unroll
  for (int r = 0; r < 4; ++r) { m[r] = -1e30f; den[r] = 0.f; }
  f32x4 acc[4] = {};
  const f32x4 kZero = {0.f, 0.f, 0.f, 0.f};

  for (int t = 0; t < 16; ++t) {
    const int r0 = t * 64;
    __syncthreads();  // all prior-iter LDS reads done
    // ---- stage K, Vt, PE ----
    {
      const int row = tid >> 2, c0 = (tid & 3) * 16;
      const unsigned short* ksrc = Kg + ((size_t)bh * 1024 + r0 + row) * 64 + c0;
      const u16x8 k0 = *(const u16x8*)ksrc;
      const u16x8 k1 = *(const u16x8*)(ksrc + 8);
      *(u16x8*)&Ks[row * 72 + c0] = k0;
      *(u16x8*)&Ks[row * 72 + c0 + 8] = k1;
      const unsigned short* vsrc = Vtg + ((size_t)bh * 64 + row) * 1024 + r0 + c0;
      const u16x8 v0 = *(const u16x8*)vsrc;
      const u16x8 v1 = *(const u16x8*)(vsrc + 8);
      *(u16x8*)&Vts[row * 72 + c0] = v0;
      *(u16x8*)&Vts[row * 72 + c0 + 8] = v1;
      const int prow = tid >> 1, pc0 = (tid & 1) * 32;
      const int pbase = l0 - r0 + 960;
      const unsigned short* psrc = PEg + (size_t)(pbase + prow) * 64 + pc0;
#pragma unroll
      for (int j = 0; j < 4; ++j) {
        const u16x8 pv = *(const u16x8*)(psrc + j * 8);
        *(u16x8*)&PEs[prow * 72 + pc0 + j * 8] = pv;
      }
    }
    __syncthreads();

    // ---- phase 2: U/W GEMM (waves 0,1 -> U; 2,3 -> W) + Sqk (all waves) ----
    f32x4 uw[2][8] = {};
    if (wid < 2) {
#pragma unroll
      for (int ks = 0; ks < 2; ++ks)
#pragma unroll
        for (int cb = 0; cb < 8; ++cb) {
          const bf16x8 pb = *(const bf16x8*)&PEs[(cb * 16 + lrow) * 72 + ks * 32 + lgrp * 8];
#pragma unroll
          for (int rb = 0; rb < 2; ++rb)
            uw[rb][cb] = __builtin_amdgcn_mfma_f32_16x16x32_bf16(qaU[rb][ks], pb, uw[rb][cb], 0, 0, 0);
        }
    } else {
#pragma unroll
      for (int ks = 0; ks < 2; ++ks) {
        bf16x8 ka[2];
#pragma unroll
        for (int rb = 0; rb < 2; ++rb)
          ka[rb] = *(const bf16x8*)&Ks[(rbase + rb * 16 + lrow) * 72 + ks * 32 + lgrp * 8];
#pragma unroll
        for (int cb = 0; cb < 8; ++cb) {
          const bf16x8 pb = *(const bf16x8*)&PEs[(cb * 16 + lrow) * 72 + ks * 32 + lgrp * 8];
#pragma unroll
          for (int rb = 0; rb < 2; ++rb)
            uw[rb][cb] = __builtin_amdgcn_mfma_f32_16x16x32_bf16(ka[rb], pb, uw[rb][cb], 0, 0, 0);
        }
      }
    }
    f32x4 sc[4];
#pragma unroll
    for (int cb = 0; cb < 4; ++cb) sc[cb] = kZero;
#pragma unroll
    for (int ks = 0; ks < 2; ++ks)
#pragma unroll
      for (int cb = 0; cb < 4; ++cb) {
        const bf16x8 kb = *(const bf16x8*)&Ks[(cb * 16 + lrow) * 72 + ks * 32 + lgrp * 8];
        sc[cb] = __builtin_amdgcn_mfma_f32_16x16x32_bf16(qaS[ks], kb, sc[cb], 0, 0, 0);
      }
    // write U/W C-frags to LDS (bf16)
    {
      unsigned short* buf = (wid < 2) ? Ub : Wb;
#pragma unroll
      for (int rb = 0; rb < 2; ++rb)
#pragma unroll
        for (int cb = 0; cb < 8; ++cb)
#pragma unroll
          for (int reg = 0; reg < 4; ++reg)
            buf[(rbase + rb * 16 + lgrp * 4 + reg) * 132 + cb * 16 + lrow] = f2bf(uw[rb][cb][reg]);
    }
    __syncthreads();

    // ---- phase 3: gather + softmax + P + PV ----
#pragma unroll
    for (int cb = 0; cb < 4; ++cb)
#pragma unroll
      for (int reg = 0; reg < 4; ++reg) {
        const int l = wid * 16 + lgrp * 4 + reg;
        const int r = cb * 16 + lrow;
        const int p = l - r + 63;
        const float s = (sc[cb][reg] + bf2f(Ub[l * 132 + p]) + bf2f(Wb[r * 132 + p])) * 0.125f;
        sc[cb][reg] = s;
      }
    float rmax[4];
#pragma unroll
    for (int reg = 0; reg < 4; ++reg)
      rmax[reg] = fmaxf(fmaxf(sc[0][reg], sc[1][reg]), fmaxf(sc[2][reg], sc[3][reg]));
#pragma unroll
    for (int reg = 0; reg < 4; ++reg) {
      rmax[reg] = fmaxf(rmax[reg], __shfl_xor(rmax[reg], 1));
      rmax[reg] = fmaxf(rmax[reg], __shfl_xor(rmax[reg], 2));
      rmax[reg] = fmaxf(rmax[reg], __shfl_xor(rmax[reg], 4));
      rmax[reg] = fmaxf(rmax[reg], __shfl_xor(rmax[reg], 8));
    }
    float fr[4], ps[4];
#pragma unroll
    for (int reg = 0; reg < 4; ++reg) {
      const float mn = fmaxf(m[reg], rmax[reg]);
      fr[reg] = __expf(m[reg] - mn);
      m[reg] = mn;
      ps[reg] = 0.f;
    }
#pragma unroll
    for (int cb = 0; cb < 4; ++cb)
#pragma unroll
      for (int reg = 0; reg < 4; ++reg) {
        const float p = __expf(sc[cb][reg] - m[reg]);
        Ps[(wid * 16 + lgrp * 4 + reg) * 72 + cb * 16 + lrow] = f2bf(p);
        ps[reg] += p;
      }
#pragma unroll
    for (int reg = 0; reg < 4; ++reg) {
      ps[reg] += __shfl_xor(ps[reg], 1);
      ps[reg] += __shfl_xor(ps[reg], 2);
      ps[reg] += __shfl_xor(ps[reg], 4);
      ps[reg] += __shfl_xor(ps[reg], 8);
      den[reg] = den[reg] * fr[reg] + ps[reg];
    }
#pragma unroll
    for (int cb = 0; cb < 4; ++cb)
#pragma unroll
      for (int reg = 0; reg < 4; ++reg) acc[cb][reg] *= fr[reg];
    // PV: own rows only — no barrier needed (same-wave LDS RAW handled by waitcnt)
#pragma unroll
    for (int ks = 0; ks < 2; ++ks) {
      const bf16x8 pa = *(const bf16x8*)&Ps[(wid * 16 + lrow) * 72 + ks * 32 + lgrp * 8];
#pragma unroll
      for (int cb = 0; cb < 4; ++cb) {
        const bf16x8 vb = *(const bf16x8*)&Vts[(cb * 16 + lrow) * 72 + ks * 32 + lgrp * 8];
        acc[cb] = __builtin_amdgcn_mfma_f32_16x16x32_bf16(pa, vb, acc[cb], 0, 0, 0);
      }
    }
  }

  // ---- epilogue ----
#pragma unroll
  for (int cb = 0; cb < 4; ++cb)
#pragma unroll
    for (int reg = 0; reg < 4; ++reg) {
      const int l = wid * 16 + lgrp * 4 + reg;
      const int d = cb * 16 + lrow;
      out[((size_t)b * 1024 + l0 + l) * 1024 + h * 64 + d] = acc[cb][reg] / den[reg];
    }
}

extern "C" void kernel_launch(void* const* d_in, const int* in_sizes, int n_in,
                              void* d_out, int out_size, void* d_ws, size_t ws_size,
                              hipStream_t stream) {
  const float* hs = (const float*)d_in[0];
  const float* wq = (const float*)d_in[1];
  const float* bq = (const float*)d_in[2];
  const float* wk = (const float*)d_in[3];
  const float* bk = (const float*)d_in[4];
  const float* wvp = (const float*)d_in[5];
  const float* bv = (const float*)d_in[6];
  const float* de = (const float*)d_in[7];

  unsigned short* wsb = (unsigned short*)d_ws;
  unsigned short* q = wsb;                      // 4 Mi bf16
  unsigned short* k = wsb + 4194304;
  unsigned short* v = wsb + 8388608;
  unsigned short* vt = wsb + 12582912;
  unsigned short* db = wsb + 16777216;          // 131008 bf16

  proj_mfma<<<dim3(32, 8, 3), 256, 0, stream>>>(hs, wq, bq, wk, bk, wvp, bv, wsb);
  cvt_dist<<<dim3(128), 256, 0, stream>>>(de, db);
  transpose_v<<<dim3(64, 16), 256, 0, stream>>>(v, vt);
  attn_mfma<<<dim3(64, 16), 256, 0, stream>>>(q, k, vt, db, (float*)d_out);
}

// Round 4
// 310.901 us; speedup vs baseline: 3.2840x; 1.3754x over previous
//
#include <hip/hip_runtime.h>

typedef __attribute__((ext_vector_type(8))) short bf16x8;
typedef __attribute__((ext_vector_type(4))) float f32x4;
typedef __attribute__((ext_vector_type(4))) unsigned short u16x4;
typedef __attribute__((ext_vector_type(8))) unsigned short u16x8;

namespace {
constexpr size_t OFF_Q = 0;
constexpr size_t OFF_K = 4194304;
constexpr size_t OFF_VT = 8388608;
constexpr size_t OFF_DB = 12582912;   // dist bf16 (131008)
constexpr size_t OFF_XB = 12713920;   // X bf16 (4194304)
constexpr size_t OFF_WB = 16908224;   // Wq|Wk|Wv bf16 (3x1048576)
}

__device__ __forceinline__ unsigned short f2bf(float f) {
  union { float f; unsigned u; } v; v.f = f;
  unsigned r = v.u + 0x7FFFu + ((v.u >> 16) & 1u);  // RNE
  return (unsigned short)(r >> 16);
}
__device__ __forceinline__ float bf2f(unsigned short h) {
  union { unsigned u; float f; } v; v.u = ((unsigned)h) << 16;
  return v.f;
}

// ------------- fp32 -> bf16 bulk convert: X, Wq, Wk, Wv, dist ----------------
__global__ __launch_bounds__(256) void cvt_all(
    const float* __restrict__ X, const float* __restrict__ Wq,
    const float* __restrict__ Wk, const float* __restrict__ Wv,
    const float* __restrict__ De, unsigned short* __restrict__ ws) {
  const int z = blockIdx.y;
  const float* src = z == 0 ? X : z == 1 ? Wq : z == 2 ? Wk : z == 3 ? Wv : De;
  unsigned short* dst = z == 0 ? ws + OFF_XB
                      : z == 4 ? ws + OFF_DB
                               : ws + OFF_WB + (size_t)(z - 1) * 1048576;
  const int n = z == 0 ? 4194304 : z == 4 ? 131008 : 1048576;
  const int idx = (blockIdx.x * 256 + threadIdx.x) * 8;
  if (idx < n) {
    const float4 f0 = *(const float4*)(src + idx);
    const float4 f1 = *(const float4*)(src + idx + 4);
    u16x8 o;
    o[0] = f2bf(f0.x); o[1] = f2bf(f0.y); o[2] = f2bf(f0.z); o[3] = f2bf(f0.w);
    o[4] = f2bf(f1.x); o[5] = f2bf(f1.y); o[6] = f2bf(f1.z); o[7] = f2bf(f1.w);
    *(u16x8*)(dst + idx) = o;
  }
}

// ------------- QKV projection, pure-bf16 MFMA; V emitted transposed ----------
// grid (32, 8, 3): 128x128 tile, 4 waves x 64x64, BK=64. z selects Q/K/V.
__global__ __launch_bounds__(256) void proj2(
    const unsigned short* __restrict__ Xb, const unsigned short* __restrict__ Wb3,
    const float* __restrict__ Bq, const float* __restrict__ Bk,
    const float* __restrict__ Bv, unsigned short* __restrict__ qo,
    unsigned short* __restrict__ ko, unsigned short* __restrict__ vto) {
  __shared__ unsigned short As[128 * 72];
  __shared__ unsigned short Bs[128 * 72];
  const int which = blockIdx.z;
  const unsigned short* W = Wb3 + (size_t)which * 1048576;
  const float* bias = which == 0 ? Bq : which == 1 ? Bk : Bv;
  const int m0 = blockIdx.x * 128, n0 = blockIdx.y * 128;
  const int tid = threadIdx.x;
  const int wid = tid >> 6, lane = tid & 63;
  const int lrow = lane & 15, lgrp = lane >> 4;
  const int wr0 = (wid >> 1) * 64, wc0 = (wid & 1) * 64;
  const int srow = tid >> 1, scol = (tid & 1) * 32;

  f32x4 acc[4][4] = {};
  for (int k0 = 0; k0 < 1024; k0 += 64) {
    u16x8 a[4], bb[4];
    const unsigned short* Ap = Xb + (size_t)(m0 + srow) * 1024 + k0 + scol;
    const unsigned short* Bp = W + (size_t)(n0 + srow) * 1024 + k0 + scol;
#pragma unroll
    for (int j = 0; j < 4; ++j) {
      a[j] = *(const u16x8*)(Ap + j * 8);
      bb[j] = *(const u16x8*)(Bp + j * 8);
    }
    __syncthreads();
#pragma unroll
    for (int j = 0; j < 4; ++j) {
      *(u16x8*)&As[srow * 72 + scol + j * 8] = a[j];
      *(u16x8*)&Bs[srow * 72 + scol + j * 8] = bb[j];
    }
    __syncthreads();
#pragma unroll
    for (int ks = 0; ks < 2; ++ks) {
      bf16x8 af[4], bfr[4];
#pragma unroll
      for (int rb = 0; rb < 4; ++rb)
        af[rb] = *(const bf16x8*)&As[(wr0 + rb * 16 + lrow) * 72 + ks * 32 + lgrp * 8];
#pragma unroll
      for (int cb = 0; cb < 4; ++cb)
        bfr[cb] = *(const bf16x8*)&Bs[(wc0 + cb * 16 + lrow) * 72 + ks * 32 + lgrp * 8];
#pragma unroll
      for (int rb = 0; rb < 4; ++rb)
#pragma unroll
        for (int cb = 0; cb < 4; ++cb)
          acc[rb][cb] = __builtin_amdgcn_mfma_f32_16x16x32_bf16(af[rb], bfr[cb], acc[rb][cb], 0, 0, 0);
    }
  }
  if (which < 2) {
    unsigned short* dst = (which == 0) ? qo : ko;
#pragma unroll
    for (int cb = 0; cb < 4; ++cb) {
      const int n = n0 + wc0 + cb * 16 + lrow;
      const float bval = bias[n];
      const int h = n >> 6, d = n & 63;
#pragma unroll
      for (int rb = 0; rb < 4; ++rb)
#pragma unroll
        for (int reg = 0; reg < 4; ++reg) {
          const int m = m0 + wr0 + rb * 16 + lgrp * 4 + reg;
          const int b_ = m >> 10, s_ = m & 1023;
          dst[(((size_t)(b_ * 16 + h) * 1024 + s_) << 6) | d] = f2bf(acc[rb][cb][reg] + bval);
        }
    }
  } else {  // V: write transposed [bh][d][s]
#pragma unroll
    for (int cb = 0; cb < 4; ++cb) {
      const int n = n0 + wc0 + cb * 16 + lrow;
      const float bval = bias[n];
      const int h = n >> 6, d = n & 63;
#pragma unroll
      for (int rb = 0; rb < 4; ++rb) {
        const int mb = m0 + wr0 + rb * 16 + lgrp * 4;
        const int b_ = mb >> 10, s_ = mb & 1023;
        u16x4 o;
#pragma unroll
        for (int reg = 0; reg < 4; ++reg) o[reg] = f2bf(acc[rb][cb][reg] + bval);
        *(u16x4*)(vto + ((size_t)(b_ * 16 + h) * 64 + d) * 1024 + s_) = o;
      }
    }
  }
}

// ------------- fused rel-pos attention: 8 waves, banded U/W strips -----------
// grid (64 bh, 16 q-blocks), 512 thr. QB=RB=64.
// wave w: U-strip (w<4) or W-strip (w-4); QK/PV quadrant (qr=w>>1, ch=w&1).
__global__ __launch_bounds__(512, 4) void attn8(
    const unsigned short* __restrict__ Qg, const unsigned short* __restrict__ Kg,
    const unsigned short* __restrict__ Vtg, const unsigned short* __restrict__ PEg,
    float* __restrict__ out) {
  __shared__ unsigned short Ks[64 * 72];
  __shared__ unsigned short Vts[64 * 72];
  __shared__ unsigned short PEs[128 * 72];
  __shared__ unsigned short Ub[64 * 84];  // U[l][pl], pl=(l&15)-r+63
  __shared__ unsigned short Wb[64 * 84];  // W[r][pw], pw=l-(r&15)+15
  __shared__ unsigned short Ps[64 * 72];  // Q staging, then P
  __shared__ float red[2][2][64];         // [max|sum][col-half][row]

  const int bh = blockIdx.x;
  const int l0 = blockIdx.y * 64;
  const int b = bh >> 4, h = bh & 15;
  const int tid = threadIdx.x;
  const int wid = tid >> 6, lane = tid & 63;
  const int lrow = lane & 15, lgrp = lane >> 4;
  const int qr = wid >> 1, ch = wid & 1;
  const bool isU = wid < 4;
  const int us = isU ? wid : wid - 4;

  // stage Q
  {
    const int row = tid >> 3, c0 = (tid & 7) * 8;
    *(u16x8*)&Ps[row * 72 + c0] = *(const u16x8*)(Qg + ((size_t)bh * 1024 + l0 + row) * 64 + c0);
  }
  __syncthreads();
  bf16x8 qaS[2], qaU[2];
#pragma unroll
  for (int ks = 0; ks < 2; ++ks)
    qaS[ks] = *(const bf16x8*)&Ps[(qr * 16 + lrow) * 72 + ks * 32 + lgrp * 8];
  if (isU) {
#pragma unroll
    for (int ks = 0; ks < 2; ++ks)
      qaU[ks] = *(const bf16x8*)&Ps[(us * 16 + lrow) * 72 + ks * 32 + lgrp * 8];
  }

  float m[4], den[4];
#pragma unroll
  for (int r = 0; r < 4; ++r) { m[r] = -1e30f; den[r] = 0.f; }
  f32x4 acc[2] = {};

  for (int t = 0; t < 16; ++t) {
    const int r0 = t * 64;
    __syncthreads();  // bar1: prior-tile readers done
    {
      const int row = tid >> 3, c0 = (tid & 7) * 8;
      *(u16x8*)&Ks[row * 72 + c0] = *(const u16x8*)(Kg + ((size_t)bh * 1024 + r0 + row) * 64 + c0);
      *(u16x8*)&Vts[row * 72 + c0] = *(const u16x8*)(Vtg + ((size_t)bh * 64 + row) * 1024 + r0 + c0);
      const int prow = tid >> 2, pc0 = (tid & 3) * 16;
      if (prow < 127) {
        const unsigned short* psrc = PEg + (size_t)(l0 - r0 + 960 + prow) * 64 + pc0;
        *(u16x8*)&PEs[prow * 72 + pc0] = *(const u16x8*)psrc;
        *(u16x8*)&PEs[prow * 72 + pc0 + 8] = *(const u16x8*)(psrc + 8);
      } else {
        const u16x8 zz = {0, 0, 0, 0, 0, 0, 0, 0};
        *(u16x8*)&PEs[prow * 72 + pc0] = zz;
        *(u16x8*)&PEs[prow * 72 + pc0 + 8] = zz;
      }
    }
    __syncthreads();  // bar2: tiles staged

    // ---- U/W banded GEMM: 16-row strip, 80-col pe window ----
    f32x4 uw[5] = {};
    const int pebase = isU ? us * 16 : 48 - us * 16;
    bf16x8 aUW[2];
    if (isU) { aUW[0] = qaU[0]; aUW[1] = qaU[1]; }
    else {
#pragma unroll
      for (int ks = 0; ks < 2; ++ks)
        aUW[ks] = *(const bf16x8*)&Ks[(us * 16 + lrow) * 72 + ks * 32 + lgrp * 8];
    }
#pragma unroll
    for (int ks = 0; ks < 2; ++ks)
#pragma unroll
      for (int cb = 0; cb < 5; ++cb) {
        const bf16x8 pb = *(const bf16x8*)&PEs[(pebase + cb * 16 + lrow) * 72 + ks * 32 + lgrp * 8];
        uw[cb] = __builtin_amdgcn_mfma_f32_16x16x32_bf16(aUW[ks], pb, uw[cb], 0, 0, 0);
      }
    {
      unsigned short* buf = isU ? Ub : Wb;
#pragma unroll
      for (int cb = 0; cb < 5; ++cb)
#pragma unroll
        for (int reg = 0; reg < 4; ++reg)
          buf[(us * 16 + lgrp * 4 + reg) * 84 + cb * 16 + lrow] = f2bf(uw[cb][reg]);
    }
    // ---- QK^T quadrant (independent of Ub/Wb) ----
    f32x4 sc[2] = {};
#pragma unroll
    for (int ks = 0; ks < 2; ++ks)
#pragma unroll
      for (int cb = 0; cb < 2; ++cb) {
        const bf16x8 kb = *(const bf16x8*)&Ks[(ch * 32 + cb * 16 + lrow) * 72 + ks * 32 + lgrp * 8];
        sc[cb] = __builtin_amdgcn_mfma_f32_16x16x32_bf16(qaS[ks], kb, sc[cb], 0, 0, 0);
      }
    __syncthreads();  // bar3: U/W visible

    // ---- gather + scale ----
#pragma unroll
    for (int cb = 0; cb < 2; ++cb)
#pragma unroll
      for (int reg = 0; reg < 4; ++reg) {
        const int l = qr * 16 + lgrp * 4 + reg;
        const int r = ch * 32 + cb * 16 + lrow;
        const float uu = bf2f(Ub[l * 84 + (l & 15) - r + 63]);
        const float ww = bf2f(Wb[r * 84 + l - (r & 15) + 15]);
        sc[cb][reg] = (sc[cb][reg] + uu + ww) * 0.125f;
      }
    // ---- softmax: partial max, cross-pair exchange ----
    float rmax[4];
#pragma unroll
    for (int reg = 0; reg < 4; ++reg) {
      rmax[reg] = fmaxf(sc[0][reg], sc[1][reg]);
      rmax[reg] = fmaxf(rmax[reg], __shfl_xor(rmax[reg], 1));
      rmax[reg] = fmaxf(rmax[reg], __shfl_xor(rmax[reg], 2));
      rmax[reg] = fmaxf(rmax[reg], __shfl_xor(rmax[reg], 4));
      rmax[reg] = fmaxf(rmax[reg], __shfl_xor(rmax[reg], 8));
    }
    if (lrow == 0) {
#pragma unroll
      for (int reg = 0; reg < 4; ++reg) red[0][ch][qr * 16 + lgrp * 4 + reg] = rmax[reg];
    }
    __syncthreads();  // bar4: partial maxes visible
    float fr[4], psum[4];
#pragma unroll
    for (int reg = 0; reg < 4; ++reg) {
      const int l = qr * 16 + lgrp * 4 + reg;
      const float jm = fmaxf(red[0][0][l], red[0][1][l]);
      const float mn = fmaxf(m[reg], jm);
      fr[reg] = __expf(m[reg] - mn);
      m[reg] = mn;
      psum[reg] = 0.f;
    }
#pragma unroll
    for (int cb = 0; cb < 2; ++cb)
#pragma unroll
      for (int reg = 0; reg < 4; ++reg) {
        const float p = __expf(sc[cb][reg] - m[reg]);
        Ps[(qr * 16 + lgrp * 4 + reg) * 72 + ch * 32 + cb * 16 + lrow] = f2bf(p);
        psum[reg] += p;
      }
#pragma unroll
    for (int reg = 0; reg < 4; ++reg) {
      psum[reg] += __shfl_xor(psum[reg], 1);
      psum[reg] += __shfl_xor(psum[reg], 2);
      psum[reg] += __shfl_xor(psum[reg], 4);
      psum[reg] += __shfl_xor(psum[reg], 8);
    }
    if (lrow == 0) {
#pragma unroll
      for (int reg = 0; reg < 4; ++reg) red[1][ch][qr * 16 + lgrp * 4 + reg] = psum[reg];
    }
    __syncthreads();  // bar5: sums + P visible
#pragma unroll
    for (int reg = 0; reg < 4; ++reg) {
      const int l = qr * 16 + lgrp * 4 + reg;
      den[reg] = den[reg] * fr[reg] + red[1][0][l] + red[1][1][l];
    }
#pragma unroll
    for (int cb = 0; cb < 2; ++cb)
#pragma unroll
      for (int reg = 0; reg < 4; ++reg) acc[cb][reg] *= fr[reg];
    // ---- PV ----
#pragma unroll
    for (int ks = 0; ks < 2; ++ks) {
      const bf16x8 pa = *(const bf16x8*)&Ps[(qr * 16 + lrow) * 72 + ks * 32 + lgrp * 8];
#pragma unroll
      for (int cb = 0; cb < 2; ++cb) {
        const bf16x8 vb = *(const bf16x8*)&Vts[(ch * 32 + cb * 16 + lrow) * 72 + ks * 32 + lgrp * 8];
        acc[cb] = __builtin_amdgcn_mfma_f32_16x16x32_bf16(pa, vb, acc[cb], 0, 0, 0);
      }
    }
  }

#pragma unroll
  for (int cb = 0; cb < 2; ++cb)
#pragma unroll
    for (int reg = 0; reg < 4; ++reg) {
      const int l = qr * 16 + lgrp * 4 + reg;
      const int d = ch * 32 + cb * 16 + lrow;
      out[((size_t)b * 1024 + l0 + l) * 1024 + h * 64 + d] = acc[cb][reg] / den[reg];
    }
}

extern "C" void kernel_launch(void* const* d_in, const int* in_sizes, int n_in,
                              void* d_out, int out_size, void* d_ws, size_t ws_size,
                              hipStream_t stream) {
  const float* hs = (const float*)d_in[0];
  const float* wq = (const float*)d_in[1];
  const float* bq = (const float*)d_in[2];
  const float* wk = (const float*)d_in[3];
  const float* bk = (const float*)d_in[4];
  const float* wv = (const float*)d_in[5];
  const float* bv = (const float*)d_in[6];
  const float* de = (const float*)d_in[7];

  unsigned short* wsb = (unsigned short*)d_ws;
  unsigned short* q = wsb + OFF_Q;
  unsigned short* k = wsb + OFF_K;
  unsigned short* vt = wsb + OFF_VT;
  unsigned short* db = wsb + OFF_DB;
  unsigned short* xb = wsb + OFF_XB;
  unsigned short* wb3 = wsb + OFF_WB;

  cvt_all<<<dim3(2048, 5), 256, 0, stream>>>(hs, wq, wk, wv, de, wsb);
  proj2<<<dim3(32, 8, 3), 256, 0, stream>>>(xb, wb3, bq, bk, bv, q, k, vt);
  attn8<<<dim3(64, 16), 512, 0, stream>>>(q, k, vt, db, (float*)d_out);
}

// Round 5
// 285.870 us; speedup vs baseline: 3.5716x; 1.0876x over previous
//
#include <hip/hip_runtime.h>

typedef __attribute__((ext_vector_type(8))) short bf16x8;
typedef __attribute__((ext_vector_type(4))) float f32x4;
typedef __attribute__((ext_vector_type(4))) unsigned short u16x4;
typedef __attribute__((ext_vector_type(8))) unsigned short u16x8;

namespace {
constexpr size_t OFF_Q = 0;
constexpr size_t OFF_K = 4194304;
constexpr size_t OFF_VT = 8388608;
constexpr size_t OFF_DB = 12582912;   // dist bf16 (131008)
constexpr size_t OFF_XB = 12713920;   // X bf16 (4194304)
constexpr size_t OFF_WB = 16908224;   // Wq|Wk|Wv bf16 (3x1048576)
}

__device__ __forceinline__ unsigned short f2bf(float f) {
  union { float f; unsigned u; } v; v.f = f;
  unsigned r = v.u + 0x7FFFu + ((v.u >> 16) & 1u);  // RNE
  return (unsigned short)(r >> 16);
}
__device__ __forceinline__ float bf2f(unsigned short h) {
  union { unsigned u; float f; } v; v.u = ((unsigned)h) << 16;
  return v.f;
}
__device__ __forceinline__ unsigned cvtpk(float lo, float hi) {
  unsigned r;
  asm("v_cvt_pk_bf16_f32 %0, %1, %2" : "=v"(r) : "v"(lo), "v"(hi));
  return r;
}

// ------------- fp32 -> bf16 bulk convert: X, Wq, Wk, Wv, dist ----------------
__global__ __launch_bounds__(256) void cvt_all(
    const float* __restrict__ X, const float* __restrict__ Wq,
    const float* __restrict__ Wk, const float* __restrict__ Wv,
    const float* __restrict__ De, unsigned short* __restrict__ ws) {
  const int z = blockIdx.y;
  const float* src = z == 0 ? X : z == 1 ? Wq : z == 2 ? Wk : z == 3 ? Wv : De;
  unsigned short* dst = z == 0 ? ws + OFF_XB
                      : z == 4 ? ws + OFF_DB
                               : ws + OFF_WB + (size_t)(z - 1) * 1048576;
  const int n = z == 0 ? 4194304 : z == 4 ? 131008 : 1048576;
  const int idx = (blockIdx.x * 256 + threadIdx.x) * 8;
  if (idx < n) {
    const float4 f0 = *(const float4*)(src + idx);
    const float4 f1 = *(const float4*)(src + idx + 4);
    u16x8 o;
    o[0] = f2bf(f0.x); o[1] = f2bf(f0.y); o[2] = f2bf(f0.z); o[3] = f2bf(f0.w);
    o[4] = f2bf(f1.x); o[5] = f2bf(f1.y); o[6] = f2bf(f1.z); o[7] = f2bf(f1.w);
    *(u16x8*)(dst + idx) = o;
  }
}

// ------------- QKV projection, pure-bf16 MFMA; V emitted transposed ----------
__global__ __launch_bounds__(256) void proj2(
    const unsigned short* __restrict__ Xb, const unsigned short* __restrict__ Wb3,
    const float* __restrict__ Bq, const float* __restrict__ Bk,
    const float* __restrict__ Bv, unsigned short* __restrict__ qo,
    unsigned short* __restrict__ ko, unsigned short* __restrict__ vto) {
  __shared__ unsigned short As[128 * 72];
  __shared__ unsigned short Bs[128 * 72];
  const int which = blockIdx.z;
  const unsigned short* W = Wb3 + (size_t)which * 1048576;
  const float* bias = which == 0 ? Bq : which == 1 ? Bk : Bv;
  const int m0 = blockIdx.x * 128, n0 = blockIdx.y * 128;
  const int tid = threadIdx.x;
  const int wid = tid >> 6, lane = tid & 63;
  const int lrow = lane & 15, lgrp = lane >> 4;
  const int wr0 = (wid >> 1) * 64, wc0 = (wid & 1) * 64;
  const int srow = tid >> 1, scol = (tid & 1) * 32;

  f32x4 acc[4][4] = {};
  for (int k0 = 0; k0 < 1024; k0 += 64) {
    u16x8 a[4], bb[4];
    const unsigned short* Ap = Xb + (size_t)(m0 + srow) * 1024 + k0 + scol;
    const unsigned short* Bp = W + (size_t)(n0 + srow) * 1024 + k0 + scol;
#pragma unroll
    for (int j = 0; j < 4; ++j) {
      a[j] = *(const u16x8*)(Ap + j * 8);
      bb[j] = *(const u16x8*)(Bp + j * 8);
    }
    __syncthreads();
#pragma unroll
    for (int j = 0; j < 4; ++j) {
      *(u16x8*)&As[srow * 72 + scol + j * 8] = a[j];
      *(u16x8*)&Bs[srow * 72 + scol + j * 8] = bb[j];
    }
    __syncthreads();
#pragma unroll
    for (int ks = 0; ks < 2; ++ks) {
      bf16x8 af[4], bfr[4];
#pragma unroll
      for (int rb = 0; rb < 4; ++rb)
        af[rb] = *(const bf16x8*)&As[(wr0 + rb * 16 + lrow) * 72 + ks * 32 + lgrp * 8];
#pragma unroll
      for (int cb = 0; cb < 4; ++cb)
        bfr[cb] = *(const bf16x8*)&Bs[(wc0 + cb * 16 + lrow) * 72 + ks * 32 + lgrp * 8];
#pragma unroll
      for (int rb = 0; rb < 4; ++rb)
#pragma unroll
        for (int cb = 0; cb < 4; ++cb)
          acc[rb][cb] = __builtin_amdgcn_mfma_f32_16x16x32_bf16(af[rb], bfr[cb], acc[rb][cb], 0, 0, 0);
    }
  }
  if (which < 2) {
    unsigned short* dst = (which == 0) ? qo : ko;
#pragma unroll
    for (int cb = 0; cb < 4; ++cb) {
      const int n = n0 + wc0 + cb * 16 + lrow;
      const float bval = bias[n];
      const int h = n >> 6, d = n & 63;
#pragma unroll
      for (int rb = 0; rb < 4; ++rb)
#pragma unroll
        for (int reg = 0; reg < 4; ++reg) {
          const int m = m0 + wr0 + rb * 16 + lgrp * 4 + reg;
          const int b_ = m >> 10, s_ = m & 1023;
          dst[(((size_t)(b_ * 16 + h) * 1024 + s_) << 6) | d] = f2bf(acc[rb][cb][reg] + bval);
        }
    }
  } else {  // V transposed [bh][d][s]
#pragma unroll
    for (int cb = 0; cb < 4; ++cb) {
      const int n = n0 + wc0 + cb * 16 + lrow;
      const float bval = bias[n];
      const int h = n >> 6, d = n & 63;
#pragma unroll
      for (int rb = 0; rb < 4; ++rb) {
        const int mb = m0 + wr0 + rb * 16 + lgrp * 4;
        const int b_ = mb >> 10, s_ = mb & 1023;
        u16x4 o;
#pragma unroll
        for (int reg = 0; reg < 4; ++reg) o[reg] = f2bf(acc[rb][cb][reg] + bval);
        *(u16x4*)(vto + ((size_t)(b_ * 16 + h) * 64 + d) * 1024 + s_) = o;
      }
    }
  }
}

// ------------- wave-specialized fused attention ------------------------------
// grid (64 bh, 16 q-blocks), 512 thr = 8 waves.
// Waves 0-3 (consumers): own 16 q-rows full width; U strip; QK^T; softmax; PV.
// Waves 4-7 (producers): W strip; stage K/V/PE for next tile (issue-early).
struct StageRegs { u16x8 k[2]; u16x8 v[2]; u16x8 pe[4]; };

__device__ __forceinline__ void issue_loads(
    StageRegs& R, const unsigned short* Kg, const unsigned short* Vtg,
    const unsigned short* PEg, int bh, int l0, int r0, int pt) {
#pragma unroll
  for (int i = 0; i < 2; ++i) {
    const int cc = pt + 256 * i, row = cc >> 3, col = (cc & 7) * 8;
    R.k[i] = *(const u16x8*)(Kg + ((size_t)bh * 1024 + r0 + row) * 64 + col);
    R.v[i] = *(const u16x8*)(Vtg + ((size_t)bh * 64 + row) * 1024 + r0 + col);
  }
#pragma unroll
  for (int i = 0; i < 4; ++i) {
    const int cc = pt + 256 * i, row = cc >> 3, col = (cc & 7) * 8;
    if (row < 127)
      R.pe[i] = *(const u16x8*)(PEg + (size_t)(l0 - r0 + 960 + row) * 64 + col);
    else
      R.pe[i] = (u16x8){0, 0, 0, 0, 0, 0, 0, 0};
  }
}

__global__ __launch_bounds__(512, 4) void attn_ws(
    const unsigned short* __restrict__ Qg, const unsigned short* __restrict__ Kg,
    const unsigned short* __restrict__ Vtg, const unsigned short* __restrict__ PEg,
    float* __restrict__ out) {
  __shared__ unsigned short Ks[64 * 72];
  __shared__ unsigned short Vts[64 * 72];
  __shared__ unsigned short PEs[128 * 72];
  __shared__ unsigned short Ws[64 * 84];     // W[r][p-band], band base 48-16*us
  __shared__ unsigned short QUs[4 * 1408];   // per-consumer: Q strip, then U[l][p] (stride 88)
  __shared__ unsigned short Ps[4 * 1152];    // per-consumer P[l][r] (stride 72)

  const int bh = blockIdx.x;
  const int l0 = blockIdx.y * 64;
  const int b = bh >> 4, h = bh & 15;
  const int tid = threadIdx.x;
  const int wid = tid >> 6, lane = tid & 63;
  const int lrow = lane & 15, lgrp = lane >> 4;
  const bool prod = wid >= 4;
  const int us = wid - 4;          // producer strip
  const int pt = (us << 6) | lane; // producer staging slot 0..255

  StageRegs R;
  if (prod) {
    issue_loads(R, Kg, Vtg, PEg, bh, l0, 0, pt);
  } else {
    // consumers stage Q into QUs (stride 88; region w holds rows 16w..16w+15)
    const int c0 = (wid << 6) | lane;
#pragma unroll
    for (int i = 0; i < 2; ++i) {
      const int cc = c0 + 256 * i, row = cc >> 3, col = (cc & 7) * 8;
      *(u16x8*)&QUs[(row >> 4) * 1408 + (row & 15) * 88 + col] =
          *(const u16x8*)(Qg + ((size_t)bh * 1024 + l0 + row) * 64 + col);
    }
  }
  __syncthreads();  // Q staged
  bf16x8 qB[2];
  if (!prod) {
#pragma unroll
    for (int ks = 0; ks < 2; ++ks)
      qB[ks] = *(const bf16x8*)&QUs[wid * 1408 + lrow * 88 + ks * 32 + lgrp * 8];
  }

  float mrun = -1e30f, den = 0.f;
  f32x4 acc[4] = {};

  for (int t = 0; t < 16; ++t) {
    const int r0 = t << 6;
    __syncthreads();  // bar1: all tile t-1 LDS reads complete
    if (prod) {       // write staged regs to LDS
#pragma unroll
      for (int i = 0; i < 2; ++i) {
        const int cc = pt + 256 * i, row = cc >> 3, col = (cc & 7) * 8;
        *(u16x8*)&Ks[row * 72 + col] = R.k[i];
        *(u16x8*)&Vts[row * 72 + col] = R.v[i];
      }
#pragma unroll
      for (int i = 0; i < 4; ++i) {
        const int cc = pt + 256 * i, row = cc >> 3, col = (cc & 7) * 8;
        *(u16x8*)&PEs[row * 72 + col] = R.pe[i];
      }
    }
    __syncthreads();  // bar2: tile t staged

    f32x4 sc[4];
    if (!prod) {
      // ---- U strip: C[p][l] = PE_band . Q^T ; pack into QUs (wave-local) ----
#pragma unroll
      for (int cb = 0; cb < 5; ++cb) {
        f32x4 u = {0.f, 0.f, 0.f, 0.f};
#pragma unroll
        for (int ks = 0; ks < 2; ++ks) {
          const bf16x8 pe = *(const bf16x8*)&PEs[(wid * 16 + cb * 16 + lrow) * 72 + ks * 32 + lgrp * 8];
          u = __builtin_amdgcn_mfma_f32_16x16x32_bf16(pe, qB[ks], u, 0, 0, 0);
        }
        const int ubase = wid * 1408 + lrow * 88 + cb * 16 + lgrp * 4;
        *(unsigned*)&QUs[ubase] = cvtpk(u[0], u[1]);
        *(unsigned*)&QUs[ubase + 2] = cvtpk(u[2], u[3]);
      }
      // ---- QK^T transposed: sc[cb] = C[r=cb*16+lgrp*4+reg][l=lrow] ----
#pragma unroll
      for (int cb = 0; cb < 4; ++cb) sc[cb] = (f32x4){0.f, 0.f, 0.f, 0.f};
#pragma unroll
      for (int ks = 0; ks < 2; ++ks)
#pragma unroll
        for (int cb = 0; cb < 4; ++cb) {
          const bf16x8 kf = *(const bf16x8*)&Ks[(cb * 16 + lrow) * 72 + ks * 32 + lgrp * 8];
          sc[cb] = __builtin_amdgcn_mfma_f32_16x16x32_bf16(kf, qB[ks], sc[cb], 0, 0, 0);
        }
    } else {
      // ---- W strip: C[p][r] = PE_band . K_strip^T ; pack into Ws ----
      bf16x8 kB[2];
#pragma unroll
      for (int ks = 0; ks < 2; ++ks)
        kB[ks] = *(const bf16x8*)&Ks[(us * 16 + lrow) * 72 + ks * 32 + lgrp * 8];
      const int peb = 48 - us * 16;
#pragma unroll
      for (int cb = 0; cb < 5; ++cb) {
        f32x4 w = {0.f, 0.f, 0.f, 0.f};
#pragma unroll
        for (int ks = 0; ks < 2; ++ks) {
          const bf16x8 pe = *(const bf16x8*)&PEs[(peb + cb * 16 + lrow) * 72 + ks * 32 + lgrp * 8];
          w = __builtin_amdgcn_mfma_f32_16x16x32_bf16(pe, kB[ks], w, 0, 0, 0);
        }
        const int wbase = (us * 16 + lrow) * 84 + cb * 16 + lgrp * 4;
        *(unsigned*)&Ws[wbase] = cvtpk(w[0], w[1]);
        *(unsigned*)&Ws[wbase + 2] = cvtpk(w[2], w[3]);
      }
      if (t < 15) issue_loads(R, Kg, Vtg, PEg, bh, l0, r0 + 64, pt);
    }
    __syncthreads();  // bar3: Ws visible

    if (!prod) {
      // ---- gather U/W + scale ----
      const int ub = wid * 1408 + lrow * 89 + 63;  // lrow*88 + lrow + 63
#pragma unroll
      for (int cb = 0; cb < 4; ++cb)
#pragma unroll
        for (int reg = 0; reg < 4; ++reg) {
          const int r = cb * 16 + lgrp * 4 + reg;
          const float uu = bf2f(QUs[ub - r]);
          const float ww = bf2f(Ws[r * 84 + lrow + 15 - lgrp * 4 - reg]);
          sc[cb][reg] = (sc[cb][reg] + uu + ww) * 0.125f;
        }
      // ---- softmax over r (lane-local 16 + shfl 16/32) ----
      float tmax = -1e30f;
#pragma unroll
      for (int cb = 0; cb < 4; ++cb)
#pragma unroll
        for (int reg = 0; reg < 4; ++reg) tmax = fmaxf(tmax, sc[cb][reg]);
      tmax = fmaxf(tmax, __shfl_xor(tmax, 16));
      tmax = fmaxf(tmax, __shfl_xor(tmax, 32));
      const float mn = fmaxf(mrun, tmax);
      const float fr = __expf(mrun - mn);
      mrun = mn;
      float psum = 0.f;
#pragma unroll
      for (int cb = 0; cb < 4; ++cb)
#pragma unroll
        for (int reg = 0; reg < 4; ++reg) {
          const float p = __expf(sc[cb][reg] - mn);
          sc[cb][reg] = p;
          psum += p;
        }
      psum += __shfl_xor(psum, 16);
      psum += __shfl_xor(psum, 32);
      den = den * fr + psum;
      // ---- pack P (pairs adjacent in r) ----
#pragma unroll
      for (int cb = 0; cb < 4; ++cb) {
        const int pb = wid * 1152 + lrow * 72 + cb * 16 + lgrp * 4;
        *(unsigned*)&Ps[pb] = cvtpk(sc[cb][0], sc[cb][1]);
        *(unsigned*)&Ps[pb + 2] = cvtpk(sc[cb][2], sc[cb][3]);
      }
#pragma unroll
      for (int cb = 0; cb < 4; ++cb)
#pragma unroll
        for (int reg = 0; reg < 4; ++reg) acc[cb][reg] *= fr;
      // ---- PV: C[d][l] += Vt . P^T (wave-local P) ----
#pragma unroll
      for (int ks = 0; ks < 2; ++ks) {
        const bf16x8 pB = *(const bf16x8*)&Ps[wid * 1152 + lrow * 72 + ks * 32 + lgrp * 8];
#pragma unroll
        for (int cb = 0; cb < 4; ++cb) {
          const bf16x8 vA = *(const bf16x8*)&Vts[(cb * 16 + lrow) * 72 + ks * 32 + lgrp * 8];
          acc[cb] = __builtin_amdgcn_mfma_f32_16x16x32_bf16(vA, pB, acc[cb], 0, 0, 0);
        }
      }
    }
  }

  if (!prod) {
    const float inv = 1.f / den;
    float* orow = out + ((size_t)b * 1024 + l0 + wid * 16 + lrow) * 1024 + h * 64;
#pragma unroll
    for (int cb = 0; cb < 4; ++cb) {
      float4 o;
      o.x = acc[cb][0] * inv; o.y = acc[cb][1] * inv;
      o.z = acc[cb][2] * inv; o.w = acc[cb][3] * inv;
      *(float4*)(orow + cb * 16 + lgrp * 4) = o;
    }
  }
}

extern "C" void kernel_launch(void* const* d_in, const int* in_sizes, int n_in,
                              void* d_out, int out_size, void* d_ws, size_t ws_size,
                              hipStream_t stream) {
  const float* hs = (const float*)d_in[0];
  const float* wq = (const float*)d_in[1];
  const float* bq = (const float*)d_in[2];
  const float* wk = (const float*)d_in[3];
  const float* bk = (const float*)d_in[4];
  const float* wv = (const float*)d_in[5];
  const float* bv = (const float*)d_in[6];
  const float* de = (const float*)d_in[7];

  unsigned short* wsb = (unsigned short*)d_ws;
  unsigned short* q = wsb + OFF_Q;
  unsigned short* k = wsb + OFF_K;
  unsigned short* vt = wsb + OFF_VT;
  unsigned short* db = wsb + OFF_DB;
  unsigned short* xb = wsb + OFF_XB;
  unsigned short* wb3 = wsb + OFF_WB;

  cvt_all<<<dim3(2048, 5), 256, 0, stream>>>(hs, wq, wk, wv, de, wsb);
  proj2<<<dim3(32, 8, 3), 256, 0, stream>>>(xb, wb3, bq, bk, bv, q, k, vt);
  attn_ws<<<dim3(64, 16), 512, 0, stream>>>(q, k, vt, db, (float*)d_out);
}